// Round 8
// baseline (279.795 us; speedup 1.0000x reference)
//
#include <hip/hip_runtime.h>
#include <stdint.h>

#define DIM   384
#define NH    8
#define HD    48
#define NTOK  4096
#define KDIM  384
// 1/sqrt(48) * log2(e): q pre-scaled so softmax uses exp2 (v_exp_f32) directly
#define SCALEL2E 0.20823509610f

typedef float  f32x4   __attribute__((ext_vector_type(4)));
typedef float  f32x16  __attribute__((ext_vector_type(16)));
typedef __bf16 bf16x8  __attribute__((ext_vector_type(8)));

#if __has_builtin(__builtin_amdgcn_exp2f)
#define EXP2F(x) __builtin_amdgcn_exp2f(x)
#else
#define EXP2F(x) exp2f(x)
#endif

__device__ __forceinline__ unsigned short f2bf(float f) {
  union { float f; unsigned int u; } c; c.f = f;
  unsigned int r = (c.u + 0x7FFFu + ((c.u >> 16) & 1u)) >> 16;  // RNE
  return (unsigned short)r;
}
__device__ __forceinline__ float bf2f(unsigned short h) {
  union { unsigned int u; float f; } c; c.u = ((unsigned int)h) << 16;
  return c.f;
}

// ws layout (bytes):
//   x_bf @ 0        : 8192*384*2     = 6,291,456
//   w_bf @ 6291456  : 1152*384*2     =   884,736
//   qc   @ 7176192  : 2*8*4096*48*2  = 6,291,456   [b,h,n,48] bf16, scaled by SCALEL2E
//   kc   @ 13467648 : 6,291,456                     [b,h,n,48] bf16
//   v_t  @ 19759104 : 2*384*4096*2   = 6,291,456   [b,c,n] bf16
// total ~26.1 MB (R1 used 30.2 MB successfully -> ws_size >= 30.2 MB; small
// OOB garbage reads past v_t stay inside ws)

// ---------------- prep: f32->bf16 conversions -------------------------------
__global__ void prep_kernel(const float* __restrict__ x, const float* __restrict__ w,
                            unsigned short* __restrict__ x_bf,
                            unsigned short* __restrict__ w_bf) {
  int tid = blockIdx.x * blockDim.x + threadIdx.x;
  int stride = gridDim.x * blockDim.x;
  for (int i = tid; i < 786432; i += stride) {
    float4 v = ((const float4*)x)[i];
    ushort4 o;
    o.x = f2bf(v.x); o.y = f2bf(v.y); o.z = f2bf(v.z); o.w = f2bf(v.w);
    ((ushort4*)x_bf)[i] = o;
  }
  for (int i = tid; i < 110592; i += stride) {
    float4 v = ((const float4*)w)[i];
    ushort4 o;
    o.x = f2bf(v.x); o.y = f2bf(v.y); o.z = f2bf(v.z); o.w = f2bf(v.w);
    ((ushort4*)w_bf)[i] = o;
  }
}

// ---------------- QKV GEMM: 8192 x 1152, K=384, 128x64 tiles ---------------
__global__ __launch_bounds__(256) void qkv_gemm(
    const unsigned short* __restrict__ A,    // x_bf [8192][384]
    const unsigned short* __restrict__ Bw,   // w_bf [1152][384]  (B^T)
    const float* __restrict__ bias,          // [1152]
    unsigned short* __restrict__ qc,
    unsigned short* __restrict__ kc,
    unsigned short* __restrict__ v_t) {
  __shared__ unsigned short ldsA[128 * 32];
  __shared__ unsigned short ldsB[64 * 32];
  __shared__ unsigned short ebuf[64 * 72];   // epilogue transpose buffer
  const int tid = threadIdx.x;
  const int wv = tid >> 6, ln = tid & 63;
  const int lrow = ln & 15, lq = ln >> 4;
  const int m0 = blockIdx.x * 128;
  const int n0 = blockIdx.y * 64;
  const int wm = (wv >> 1) * 64, wn = (wv & 1) * 32;

  f32x4 acc[4][2];
#pragma unroll
  for (int mi = 0; mi < 4; ++mi)
#pragma unroll
    for (int ni = 0; ni < 2; ++ni)
#pragma unroll
      for (int r = 0; r < 4; ++r) acc[mi][ni][r] = 0.f;

  for (int k0 = 0; k0 < KDIM; k0 += 32) {
    __syncthreads();
#pragma unroll
    for (int j = 0; j < 2; ++j) {
      int r16 = wv * 2 + j;
      const unsigned short* ga = A + (size_t)(m0 + r16 * 16 + (ln >> 2)) * KDIM
                                   + k0 + (ln & 3) * 8;
      __builtin_amdgcn_global_load_lds(
          (const __attribute__((address_space(1))) void*)ga,
          (__attribute__((address_space(3))) void*)&ldsA[r16 * 512], 16, 0, 0);
    }
    const unsigned short* gb = Bw + (size_t)(n0 + wv * 16 + (ln >> 2)) * KDIM
                                  + k0 + (ln & 3) * 8;
    __builtin_amdgcn_global_load_lds(
        (const __attribute__((address_space(1))) void*)gb,
        (__attribute__((address_space(3))) void*)&ldsB[wv * 512], 16, 0, 0);
    __syncthreads();
    bf16x8 af[4], bfv[2];
#pragma unroll
    for (int mi = 0; mi < 4; ++mi)
      af[mi] = *(const bf16x8*)&ldsA[(wm + mi * 16 + lrow) * 32 + lq * 8];
#pragma unroll
    for (int ni = 0; ni < 2; ++ni)
      bfv[ni] = *(const bf16x8*)&ldsB[(wn + ni * 16 + lrow) * 32 + lq * 8];
#pragma unroll
    for (int mi = 0; mi < 4; ++mi)
#pragma unroll
      for (int ni = 0; ni < 2; ++ni)
        acc[mi][ni] = __builtin_amdgcn_mfma_f32_16x16x32_bf16(
            af[mi], bfv[ni], acc[mi][ni], 0, 0, 0);
  }

  // ---- epilogue: C-tile half -> ebuf (bf16) -> 16B vector stores ----
  const int region = (n0 >= 768) ? 2 : (n0 >= 384 ? 1 : 0);   // q/k/v, block-uniform
  const float scl = (region == 0) ? SCALEL2E : 1.0f;
  const float bias0 = bias[n0 + wn + lrow];
  const float bias1 = bias[n0 + wn + 16 + lrow];

#pragma unroll
  for (int half = 0; half < 2; ++half) {
    __syncthreads();
    if ((wv >> 1) == half) {
#pragma unroll
      for (int mi = 0; mi < 4; ++mi)
#pragma unroll
        for (int ni = 0; ni < 2; ++ni)
#pragma unroll
          for (int r = 0; r < 4; ++r) {
            int row = mi * 16 + lq * 4 + r;        // 0..63 within half
            int col = wn + ni * 16 + lrow;         // 0..63
            float val = (acc[mi][ni][r] + (ni ? bias1 : bias0)) * scl;
            ebuf[row * 72 + col] = f2bf(val);
          }
    }
    __syncthreads();
    if (region < 2) {
      unsigned short* dst = (region == 0) ? qc : kc;
      const int obase = n0 - region * 384;
#pragma unroll
      for (int i = 0; i < 2; ++i) {
        int id = tid + i * 256;                    // 0..511 = 64 rows x 8 chunks
        int row = id >> 3, cc = id & 7;
        uint4 val = *(const uint4*)&ebuf[row * 72 + cc * 8];
        int nrow = m0 + half * 64 + row;
        int b = nrow >> 12, nn = nrow & 4095;
        int o = obase + cc * 8;
        int h = o / 48, d = o - h * 48;            // 8-chunk never straddles h
        *(uint4*)&dst[((size_t)(b * 8 + h) * NTOK + nn) * HD + d] = val;
      }
    } else {
#pragma unroll
      for (int i = 0; i < 2; ++i) {
        int id = tid + i * 256;                    // 0..511 = 64 cols x 8 row-chunks
        int col = id & 63, rc = id >> 6;
        int r0 = rc * 8;
        ushort4 lo, hi;
        lo.x = ebuf[(r0 + 0) * 72 + col]; lo.y = ebuf[(r0 + 1) * 72 + col];
        lo.z = ebuf[(r0 + 2) * 72 + col]; lo.w = ebuf[(r0 + 3) * 72 + col];
        hi.x = ebuf[(r0 + 4) * 72 + col]; hi.y = ebuf[(r0 + 5) * 72 + col];
        hi.z = ebuf[(r0 + 6) * 72 + col]; hi.w = ebuf[(r0 + 7) * 72 + col];
        uint4 pk;
        pk.x = (unsigned int)lo.x | ((unsigned int)lo.y << 16);
        pk.y = (unsigned int)lo.z | ((unsigned int)lo.w << 16);
        pk.z = (unsigned int)hi.x | ((unsigned int)hi.y << 16);
        pk.w = (unsigned int)hi.z | ((unsigned int)hi.w << 16);
        int nrow = m0 + half * 64 + r0;
        int b = nrow >> 12;
        int o = n0 - 768 + col;
        *(uint4*)&v_t[((size_t)(b * DIM + o)) * NTOK + (nrow & 4095)] = pk;
      }
    }
  }
}

// ---------------- LePE: depthwise 3x3, coalesced output (writes out base) --
__global__ __launch_bounds__(256) void lepe_kernel(
    const unsigned short* __restrict__ v_t,
    const float* __restrict__ lw, const float* __restrict__ lb,
    float* __restrict__ out) {
  __shared__ __align__(16) unsigned short pl[16 * 648];
  const int cg = blockIdx.x;      // 0..23
  const int sy = blockIdx.y;      // 0..7
  const int b  = blockIdx.z;      // 0..1
  const int t = threadIdx.x;
  const int y0 = sy * 8;
#pragma unroll
  for (int i = 0; i < 5; ++i) {
    int id = t + i * 256;                      // 0..1279
    int c = id / 80, rem = id - c * 80;
    int row = rem >> 3, cx = rem & 7;
    int y = y0 - 1 + row;
    uint4 val = make_uint4(0u, 0u, 0u, 0u);
    if (y >= 0 && y < 64)
      val = *(const uint4*)(v_t + ((size_t)(b * DIM + cg * 16 + c)) * NTOK + y * 64 + cx * 8);
    *(uint4*)&pl[c * 648 + row * 64 + cx * 8] = val;
  }
  __syncthreads();
  const int c = t & 15, pg = t >> 4;
  const int cglob = cg * 16 + c;
  float w[9];
#pragma unroll
  for (int j = 0; j < 9; ++j) w[j] = lw[cglob * 9 + j];
  const float bias = lb[cglob];
  const unsigned short* base = &pl[c * 648];
  for (int i = 0; i < 32; ++i) {
    int p = pg * 32 + i;
    int lr = p >> 6, x = p & 63;
    float acc = bias;
#pragma unroll
    for (int ky = 0; ky < 3; ++ky)
#pragma unroll
      for (int kx = 0; kx < 3; ++kx) {
        int xx = x + kx - 1;
        if (xx >= 0 && xx < 64)
          acc += w[ky * 3 + kx] * bf2f(base[(lr + ky) * 64 + xx]);
      }
    out[((size_t)(b * NTOK + sy * 512 + p)) * DIM + cglob] = acc;
  }
}

// ---------------- flash attention: wave-private quarters, NO loop barriers --
// block 256 = 4 waves; wave kh owns key-quarter kh*1024..+1024 (32-key tiles)
// for the block's 64 qrows (2 sets x 32). Each wave stages K/V into its OWN
// LDS region -> within-wave DS ordering only, zero __syncthreads in the loop.
// S^T = K*Q^T (lane l31 = qrow, regs = keys); permuted-key PV (R7-proven,
// zero lane exchange); lsum = per-lane adds fused with exp2.
// Epilogue: 3-barrier tree combine of the 4 quarter-partials through LDS.
// grid 64x16 = 1024 blocks; __launch_bounds__(256,3) -> 12 waves/CU.
__global__ __launch_bounds__(256, 3) void attn_kernel(
    const unsigned short* __restrict__ qc,
    const unsigned short* __restrict__ kcg,
    const unsigned short* __restrict__ v_t,
    float* __restrict__ out) {
  __shared__ __align__(16) char smem[33056];
  unsigned short* Kl = (unsigned short*)smem;            // [4][32*64] 16384 B, XOR-swizzled
  unsigned short* Vl = (unsigned short*)(smem + 16384);  // [4][49*36] +1.5K read-slack
  float* Lsum = (float*)(smem + 32032);                  // [4][64]
  float* bufA = (float*)smem;                            // [64][48] epilogue (aliases Kl)
  float* bufB = (float*)(smem + 12288);                  // [64][48]

  const int tid = threadIdx.x;
  const int kh = tid >> 6;         // wave = key-quarter
  const int ln = tid & 63;
  const int l31 = ln & 31, hh = ln >> 5;
  const int qb = blockIdx.x;       // 0..63  (64 qrows each)
  const int bh = blockIdx.y;
  const int b = bh >> 3, hd = bh & 7;

  unsigned short* Kh = Kl + kh * 2048;   // 32 rows x 64 shorts
  unsigned short* Vh = Vl + kh * 1764;   // 49 rows x 36 shorts

  // staging offsets (loop-invariant, per 64-lane wave)
  // K: 32 rows x 6 chunks (8 shorts) -> XOR-swizzled slot (cc ^ (r&7))
  // V: 48 rows x 4 chunks -> pad-stride 36
  int kwo[3], kgo[3], vwo[3], vgo[3];
#pragma unroll
  for (int i = 0; i < 3; ++i) {
    int idx = ln + i * 64;               // 0..191
    int r = idx / 6, cc = idx - r * 6;
    kwo[i] = r * 64 + ((cc ^ (r & 7)) * 8);
    kgo[i] = r * 48 + cc * 8;
    int vd = idx >> 2, c4 = idx & 3;
    vwo[i] = vd * 36 + c4 * 8;
    vgo[i] = vd * 4096 + c4 * 8;
  }

  // Q fragments: 2 sets x (lane's own qrow, 3 hd-chunks of 16)
  bf16x8 Qf[2][3];
#pragma unroll
  for (int set = 0; set < 2; ++set) {
    const int qrow = qb * 64 + set * 32 + l31;
    const unsigned short* qp = qc + ((size_t)bh * NTOK + qrow) * HD + hh * 8;
#pragma unroll
    for (int hs = 0; hs < 3; ++hs)
      Qf[set][hs] = *(const bf16x8*)(qp + hs * 16);
  }

  f32x16 Oacc[2][2];
#pragma unroll
  for (int set = 0; set < 2; ++set)
#pragma unroll
    for (int dc = 0; dc < 2; ++dc)
#pragma unroll
      for (int r = 0; r < 16; ++r) Oacc[set][dc][r] = 0.f;
  float lsum0 = 0.f, lsum1 = 0.f;

  const unsigned short* kbase = kcg + (size_t)bh * NTOK * HD;
  const unsigned short* vbase = v_t + ((size_t)b * DIM + hd * HD) * NTOK;

  // prologue: prefetch first tile of this wave's quarter into registers
  uint4 kr0, kr1, kr2, vr0, vr1, vr2;
  {
    const unsigned short* kg = kbase + (size_t)(kh * 32) * 32 * HD;
    const unsigned short* vg = vbase + (kh * 32) * 32;
    kr0 = *(const uint4*)(kg + kgo[0]);
    kr1 = *(const uint4*)(kg + kgo[1]);
    kr2 = *(const uint4*)(kg + kgo[2]);
    vr0 = *(const uint4*)(vg + vgo[0]);
    vr1 = *(const uint4*)(vg + vgo[1]);
    vr2 = *(const uint4*)(vg + vgo[2]);
  }

  for (int it = 0; it < 32; ++it) {
    // stage this tile (wave-private: no barrier, DS in-order within wave)
    *(uint4*)&Kh[kwo[0]] = kr0;
    *(uint4*)&Kh[kwo[1]] = kr1;
    *(uint4*)&Kh[kwo[2]] = kr2;
    *(uint4*)&Vh[vwo[0]] = vr0;
    *(uint4*)&Vh[vwo[1]] = vr1;
    *(uint4*)&Vh[vwo[2]] = vr2;
    {                                    // issue next-tile loads under compute
      int ktn = kh * 32 + ((it + 1) & 31);   // wrap: in-bounds, same work
      const unsigned short* kg = kbase + (size_t)ktn * 32 * HD;
      const unsigned short* vg = vbase + ktn * 32;
      kr0 = *(const uint4*)(kg + kgo[0]);
      kr1 = *(const uint4*)(kg + kgo[1]);
      kr2 = *(const uint4*)(kg + kgo[2]);
      vr0 = *(const uint4*)(vg + vgo[0]);
      vr1 = *(const uint4*)(vg + vgo[1]);
      vr2 = *(const uint4*)(vg + vgo[2]);
    }

    // S^T = K * Q^T for both Q sets (3 K=16 steps, shared kf)
    f32x16 sA, sB;
#pragma unroll
    for (int r = 0; r < 16; ++r) { sA[r] = 0.f; sB[r] = 0.f; }
    const unsigned short* kr = &Kh[l31 * 64];
    const int rx = l31 & 7;
#pragma unroll
    for (int hs = 0; hs < 3; ++hs) {
      bf16x8 kf = *(const bf16x8*)&kr[((hs * 2 + hh) ^ rx) * 8];
      sA = __builtin_amdgcn_mfma_f32_32x32x16_bf16(kf, Qf[0][hs], sA, 0, 0, 0);
      sB = __builtin_amdgcn_mfma_f32_32x32x16_bf16(kf, Qf[1][hs], sB, 0, 0, 0);
    }
    // exp2 + pack bf16 pairs + per-lane lsum (lane l31 = qrow; regs = keys)
    unsigned int PA[8], PB[8];
#pragma unroll
    for (int t8 = 0; t8 < 8; ++t8) {
      float a0 = EXP2F(sA[2 * t8]);
      float a1 = EXP2F(sA[2 * t8 + 1]);
      lsum0 += a0 + a1;
      PA[t8] = __builtin_amdgcn_perm(__float_as_uint(a1), __float_as_uint(a0),
                                     0x07060302u);
      float b0 = EXP2F(sB[2 * t8]);
      float b1 = EXP2F(sB[2 * t8 + 1]);
      lsum1 += b0 + b1;
      PB[t8] = __builtin_amdgcn_perm(__float_as_uint(b1), __float_as_uint(b0),
                                     0x07060302u);
    }
    // O += P*V, permuted key order (A = 4 consecutive P words, by-value casts)
#pragma unroll
    for (int u = 0; u < 2; ++u) {
      bf16x8 pav0 = __builtin_bit_cast(bf16x8,
          make_uint4(PA[4 * u + 0], PA[4 * u + 1], PA[4 * u + 2], PA[4 * u + 3]));
      bf16x8 pav1 = __builtin_bit_cast(bf16x8,
          make_uint4(PB[4 * u + 0], PB[4 * u + 1], PB[4 * u + 2], PB[4 * u + 3]));
      const int goff = (4 * u + hh) * 4;       // key-groups g, g+2
#pragma unroll
      for (int dc = 0; dc < 2; ++dc) {
        const int vrow = dc * 32 + l31;        // rows 48.. = garbage, discarded
        const unsigned short* vrp = &Vh[vrow * 36 + goff];
        uint2 g0 = *(const uint2*)(vrp);
        uint2 g2 = *(const uint2*)(vrp + 8);
        bf16x8 vfv = __builtin_bit_cast(bf16x8, make_uint4(g0.x, g0.y, g2.x, g2.y));
        Oacc[0][dc] = __builtin_amdgcn_mfma_f32_32x32x16_bf16(
            pav0, vfv, Oacc[0][dc], 0, 0, 0);
        Oacc[1][dc] = __builtin_amdgcn_mfma_f32_32x32x16_bf16(
            pav1, vfv, Oacc[1][dc], 0, 0, 0);
      }
    }
  }

  // ---- epilogue: tree-combine 4 quarter-partials ----
  float ls0 = lsum0 + __shfl_xor(lsum0, 32, 64);   // fold hh halves
  float ls1 = lsum1 + __shfl_xor(lsum1, 32, 64);
  __syncthreads();                     // loop LDS dead; bufs may alias now
  if (ln < 32) {
    Lsum[kh * 64 + ln] = ls0;
    Lsum[kh * 64 + 32 + ln] = ls1;
  }
  if ((kh & 1) == 0) {                 // waves 0,2: store into bufA/bufB
    float* buf = (kh == 0) ? bufA : bufB;
#pragma unroll
    for (int set = 0; set < 2; ++set)
#pragma unroll
      for (int dc = 0; dc < 2; ++dc)
#pragma unroll
        for (int r = 0; r < 16; ++r) {
          int qrow = set * 32 + (r & 3) + 8 * (r >> 2) + 4 * hh;
          int d = dc * 32 + l31;
          if (d < HD) buf[qrow * 48 + d] = Oacc[set][dc][r];
        }
  }
  __syncthreads();
  if ((kh & 1) == 1) {                 // waves 1,3: add into bufA/bufB
    float* buf = (kh == 1) ? bufA : bufB;
#pragma unroll
    for (int set = 0; set < 2; ++set)
#pragma unroll
      for (int dc = 0; dc < 2; ++dc)
#pragma unroll
        for (int r = 0; r < 16; ++r) {
          int qrow = set * 32 + (r & 3) + 8 * (r >> 2) + 4 * hh;
          int d = dc * 32 + l31;
          if (d < HD) buf[qrow * 48 + d] += Oacc[set][dc][r];
        }
  }
  __syncthreads();
  if (kh == 0) {                       // wave 0: final sum, normalize, out +=
#pragma unroll
    for (int set = 0; set < 2; ++set)
#pragma unroll
      for (int r = 0; r < 16; ++r) {
        int qrow = set * 32 + (r & 3) + 8 * (r >> 2) + 4 * hh;
        float lt = Lsum[qrow] + Lsum[64 + qrow] + Lsum[128 + qrow] + Lsum[192 + qrow];
        float linv = 1.0f / lt;
        float* op = out + ((size_t)(b * NTOK + qb * 64 + qrow)) * DIM + hd * HD;
        op[l31] += (bufA[qrow * 48 + l31] + bufB[qrow * 48 + l31]) * linv;
        if (l31 < 16)
          op[32 + l31] += (bufA[qrow * 48 + 32 + l31] + bufB[qrow * 48 + 32 + l31]) * linv;
      }
  }
}

// ---------------------------------------------------------------------------
extern "C" void kernel_launch(void* const* d_in, const int* in_sizes, int n_in,
                              void* d_out, int out_size, void* d_ws, size_t ws_size,
                              hipStream_t stream) {
  const float* x      = (const float*)d_in[0];
  const float* qkv_w  = (const float*)d_in[1];
  const float* qkv_b  = (const float*)d_in[2];
  const float* lepe_w = (const float*)d_in[3];
  const float* lepe_b = (const float*)d_in[4];

  char* ws = (char*)d_ws;
  unsigned short* x_bf = (unsigned short*)(ws);
  unsigned short* w_bf = (unsigned short*)(ws + 6291456);
  unsigned short* qcp  = (unsigned short*)(ws + 7176192);
  unsigned short* kcp  = (unsigned short*)(ws + 13467648);
  unsigned short* v_t  = (unsigned short*)(ws + 19759104);
  float* out = (float*)d_out;

  prep_kernel<<<1024, 256, 0, stream>>>(x, qkv_w, x_bf, w_bf);
  qkv_gemm<<<dim3(64, 18), 256, 0, stream>>>(x_bf, w_bf, qkv_b, qcp, kcp, v_t);
  lepe_kernel<<<dim3(24, 8, 2), 256, 0, stream>>>(v_t, lepe_w, lepe_b, out);
  attn_kernel<<<dim3(64, 16), 256, 0, stream>>>(qcp, kcp, v_t, out);
}